// Round 1
// baseline (2437.989 us; speedup 1.0000x reference)
//
#include <hip/hip_runtime.h>
#include <math.h>

// CrissCrossAttention3D  N=2 C=256 Ci=64 T=16 H=96 W=96
// Pipeline (all fp32 this round):
//  K1 qkv   : x[n,c,p] -> qT/kT[n,p,64], vT[n,p,256]   (p = t*HW+h*W+w, c-innermost)
//  K2a/b/c  : energies -> att[n,p,208]  (0..15 t-seg, 16..111 h-seg (diag=NEG), 112..207 w-seg (diag=NEG))
//  K3       : softmax over 208 per position (one wave / position)
//  K4t/h/w  : apply -> outT[n,p,256]  (t writes, h/w accumulate)
//  K5       : transpose outT -> out[n,c,t,h,w], * gamma
// ws requirement: 849,346,560 bytes (outT overlays dead qT/kT + 151MB extension)

namespace {
constexpr int Nn = 2, Cc = 256, Tt = 16, Hh = 96, Ww = 96;
constexpr int HW = Hh * Ww;        // 9216
constexpr int THW = Tt * HW;       // 147456
constexpr int Ssz = 208;
constexpr float FNEG = -1.0e30f;

constexpr size_t QT_OFF  = 0;                       // 18,874,368 floats
constexpr size_t KT_OFF  = 18874368;                // 18,874,368 floats
constexpr size_t VT_OFF  = 75497472;                // 75,497,472 floats
constexpr size_t ATT_OFF = 150994944;               // 61,341,696 floats
constexpr size_t OUTT_OFF = 0;                      // 75,497,472 floats (overlays qT,kT,ext)
} // namespace

// ---------------- K1: QKV projection ----------------
// grid (1152, 3, 2)  block 256.  m-tile 128 (g=0: q0-63,k0-63; g=1: v0-127; g=2: v128-255)
// p-tile 128, K-tile 32.  LDS: xs[32][128] + wsm[128][33] = 33,280 B
__global__ __launch_bounds__(256) void k_qkv(
    const float* __restrict__ x,
    const float* __restrict__ Wq, const float* __restrict__ bq,
    const float* __restrict__ Wk, const float* __restrict__ bk,
    const float* __restrict__ Wv, const float* __restrict__ bv,
    float* __restrict__ qT, float* __restrict__ kT, float* __restrict__ vT)
{
    const int pt = blockIdx.x;
    const int g  = blockIdx.y;
    const int n  = blockIdx.z;
    const int tid = threadIdx.x;
    const int tx = tid & 15, ty = tid >> 4;
    const int p0 = pt * 128;

    extern __shared__ float sm[];
    float* xs  = sm;                // [32][128]
    float* wsm = sm + 32 * 128;     // [128][33]

    float acc[8][8];
#pragma unroll
    for (int a = 0; a < 8; ++a)
#pragma unroll
        for (int b = 0; b < 8; ++b) acc[a][b] = 0.f;

    for (int c0 = 0; c0 < Cc; c0 += 32) {
        // load x tile: 32 rows x 128 p (float4)
#pragma unroll
        for (int it = 0; it < 4; ++it) {
            int cl = (tid >> 5) + 8 * it;
            int p4 = (tid & 31) * 4;
            float4 xv = *(const float4*)(x + ((size_t)(n * Cc + c0 + cl)) * THW + p0 + p4);
            *(float4*)(xs + cl * 128 + p4) = xv;
        }
        // load W tile: 128 rows x 32 k
#pragma unroll
        for (int it = 0; it < 4; ++it) {
            int ml = (tid >> 3) + 32 * it;
            int k4 = (tid & 7) * 4;
            int m = g * 128 + ml;
            const float* wrow;
            if (m < 64)       wrow = Wq + (size_t)m * Cc;
            else if (m < 128) wrow = Wk + (size_t)(m - 64) * Cc;
            else              wrow = Wv + (size_t)(m - 128) * Cc;
            float4 wv = *(const float4*)(wrow + c0 + k4);
            wsm[ml * 33 + k4 + 0] = wv.x;
            wsm[ml * 33 + k4 + 1] = wv.y;
            wsm[ml * 33 + k4 + 2] = wv.z;
            wsm[ml * 33 + k4 + 3] = wv.w;
        }
        __syncthreads();
#pragma unroll 4
        for (int kk = 0; kk < 32; ++kk) {
            float xf[8], wf[8];
#pragma unroll
            for (int ip = 0; ip < 8; ++ip) xf[ip] = xs[kk * 128 + ty + 16 * ip];
#pragma unroll
            for (int im = 0; im < 8; ++im) wf[im] = wsm[(tx + 16 * im) * 33 + kk];
#pragma unroll
            for (int im = 0; im < 8; ++im)
#pragma unroll
                for (int ip = 0; ip < 8; ++ip) acc[im][ip] += wf[im] * xf[ip];
        }
        __syncthreads();
    }

#pragma unroll
    for (int im = 0; im < 8; ++im) {
        int m = g * 128 + tx + 16 * im;
        float bias; float* dst; int cdim, cloc;
        if (m < 64)       { dst = qT; cloc = m;       cdim = 64;  bias = bq[cloc]; }
        else if (m < 128) { dst = kT; cloc = m - 64;  cdim = 64;  bias = bk[cloc]; }
        else              { dst = vT; cloc = m - 128; cdim = 256; bias = bv[cloc]; }
#pragma unroll
        for (int ip = 0; ip < 8; ++ip) {
            int p = p0 + ty + 16 * ip;
            dst[((size_t)n * THW + p) * cdim + cloc] = acc[im][ip] + bias;
        }
    }
}

// ---------------- K2a: e_t ----------------
// grid (96, 96, 2) = (w, h, n).  out att[.., s=0..15]
__global__ __launch_bounds__(256) void k_et(
    const float* __restrict__ qT, const float* __restrict__ kT, float* __restrict__ att)
{
    const int w = blockIdx.x, h = blockIdx.y, n = blockIdx.z;
    const int tid = threadIdx.x;
    extern __shared__ float sm[];
    float* qs = sm;            // [16][65]
    float* ks = sm + 16 * 65;  // [16][65]
    {
        int tt = tid >> 4, c4 = (tid & 15) * 4;
        size_t base = ((size_t)(n * Tt + tt) * HW + h * Ww + w) * 64 + c4;
        float4 qv = *(const float4*)(qT + base);
        float4 kv = *(const float4*)(kT + base);
        qs[tt * 65 + c4 + 0] = qv.x; qs[tt * 65 + c4 + 1] = qv.y;
        qs[tt * 65 + c4 + 2] = qv.z; qs[tt * 65 + c4 + 3] = qv.w;
        ks[tt * 65 + c4 + 0] = kv.x; ks[tt * 65 + c4 + 1] = kv.y;
        ks[tt * 65 + c4 + 2] = kv.z; ks[tt * 65 + c4 + 3] = kv.w;
    }
    __syncthreads();
    const int t = tid >> 4, s = tid & 15;
    float acc = 0.f;
#pragma unroll 8
    for (int c = 0; c < 64; ++c) acc += qs[t * 65 + c] * ks[s * 65 + c];
    att[((size_t)(n * Tt + t) * HW + h * Ww + w) * Ssz + s] = acc;
}

// ---------------- K2b: e_h ----------------
// grid (96, 16, 2) = (w, t, n).  rows = h for q, s for k.  out att[.., 16+s], diag s==h -> NEG
__global__ __launch_bounds__(256) void k_eh(
    const float* __restrict__ qT, const float* __restrict__ kT, float* __restrict__ att)
{
    const int w = blockIdx.x, t = blockIdx.y, n = blockIdx.z;
    const int tid = threadIdx.x;
    const int tx = tid & 15, ty = tid >> 4;
    extern __shared__ float sm[];
    float* qs = sm;            // [96][65]
    float* ks = sm + 96 * 65;  // [96][65]
#pragma unroll
    for (int it = 0; it < 6; ++it) {
        int r = (tid >> 4) + 16 * it;
        int c4 = (tid & 15) * 4;
        size_t a = ((size_t)(n * Tt + t) * HW + r * Ww + w) * 64 + c4;
        float4 qv = *(const float4*)(qT + a);
        float4 kv = *(const float4*)(kT + a);
        qs[r * 65 + c4 + 0] = qv.x; qs[r * 65 + c4 + 1] = qv.y;
        qs[r * 65 + c4 + 2] = qv.z; qs[r * 65 + c4 + 3] = qv.w;
        ks[r * 65 + c4 + 0] = kv.x; ks[r * 65 + c4 + 1] = kv.y;
        ks[r * 65 + c4 + 2] = kv.z; ks[r * 65 + c4 + 3] = kv.w;
    }
    __syncthreads();
    float acc[6][6];
#pragma unroll
    for (int i = 0; i < 6; ++i)
#pragma unroll
        for (int j = 0; j < 6; ++j) acc[i][j] = 0.f;
    for (int c = 0; c < 64; ++c) {
        float qf[6], kf[6];
#pragma unroll
        for (int i = 0; i < 6; ++i) qf[i] = qs[(ty + 16 * i) * 65 + c];
#pragma unroll
        for (int j = 0; j < 6; ++j) kf[j] = ks[(tx + 16 * j) * 65 + c];
#pragma unroll
        for (int i = 0; i < 6; ++i)
#pragma unroll
            for (int j = 0; j < 6; ++j) acc[i][j] += qf[i] * kf[j];
    }
#pragma unroll
    for (int i = 0; i < 6; ++i)
#pragma unroll
        for (int j = 0; j < 6; ++j) {
            int h = ty + 16 * i, s = tx + 16 * j;
            float v = (s == h) ? FNEG : acc[i][j];
            att[((size_t)(n * Tt + t) * HW + h * Ww + w) * Ssz + 16 + s] = v;
        }
}

// ---------------- K2c: e_w ----------------
// grid (96, 16, 2) = (h, t, n).  rows = w for q, s for k.  out att[.., 112+s], diag s==w -> NEG
__global__ __launch_bounds__(256) void k_ew(
    const float* __restrict__ qT, const float* __restrict__ kT, float* __restrict__ att)
{
    const int h = blockIdx.x, t = blockIdx.y, n = blockIdx.z;
    const int tid = threadIdx.x;
    const int tx = tid & 15, ty = tid >> 4;
    extern __shared__ float sm[];
    float* qs = sm;
    float* ks = sm + 96 * 65;
    const size_t rowbase = ((size_t)(n * Tt + t) * HW + h * Ww) * 64;
#pragma unroll
    for (int it = 0; it < 6; ++it) {
        int idx = tid + it * 256;          // (r, c4): r = idx/16, c4 = (idx%16)*4
        int r = idx >> 4, c4 = (idx & 15) * 4;
        float4 qv = *(const float4*)(qT + rowbase + r * 64 + c4);
        float4 kv = *(const float4*)(kT + rowbase + r * 64 + c4);
        qs[r * 65 + c4 + 0] = qv.x; qs[r * 65 + c4 + 1] = qv.y;
        qs[r * 65 + c4 + 2] = qv.z; qs[r * 65 + c4 + 3] = qv.w;
        ks[r * 65 + c4 + 0] = kv.x; ks[r * 65 + c4 + 1] = kv.y;
        ks[r * 65 + c4 + 2] = kv.z; ks[r * 65 + c4 + 3] = kv.w;
    }
    __syncthreads();
    float acc[6][6];
#pragma unroll
    for (int i = 0; i < 6; ++i)
#pragma unroll
        for (int j = 0; j < 6; ++j) acc[i][j] = 0.f;
    for (int c = 0; c < 64; ++c) {
        float qf[6], kf[6];
#pragma unroll
        for (int i = 0; i < 6; ++i) qf[i] = qs[(ty + 16 * i) * 65 + c];
#pragma unroll
        for (int j = 0; j < 6; ++j) kf[j] = ks[(tx + 16 * j) * 65 + c];
#pragma unroll
        for (int i = 0; i < 6; ++i)
#pragma unroll
            for (int j = 0; j < 6; ++j) acc[i][j] += qf[i] * kf[j];
    }
#pragma unroll
    for (int i = 0; i < 6; ++i)
#pragma unroll
        for (int j = 0; j < 6; ++j) {
            int w = ty + 16 * i, s = tx + 16 * j;
            float v = (s == w) ? FNEG : acc[i][j];
            att[((size_t)(n * Tt + t) * HW + h * Ww + w) * Ssz + 112 + s] = v;
        }
}

// ---------------- K3: softmax over 208 ----------------
// one wave per position; grid NTHW/4, block 256
__global__ __launch_bounds__(256) void k_softmax(float* __restrict__ att)
{
    const int pos = blockIdx.x * 4 + (threadIdx.x >> 6);
    const int lane = threadIdx.x & 63;
    float* row = att + (size_t)pos * Ssz;
    float v0 = row[lane];
    float v1 = row[lane + 64];
    float v2 = row[lane + 128];
    float v3 = (lane < 16) ? row[lane + 192] : -INFINITY;
    float m = fmaxf(fmaxf(v0, v1), fmaxf(v2, v3));
#pragma unroll
    for (int k = 32; k >= 1; k >>= 1) m = fmaxf(m, __shfl_xor(m, k, 64));
    v0 = expf(v0 - m); v1 = expf(v1 - m); v2 = expf(v2 - m);
    v3 = (lane < 16) ? expf(v3 - m) : 0.f;
    float s = v0 + v1 + v2 + v3;
#pragma unroll
    for (int k = 32; k >= 1; k >>= 1) s += __shfl_xor(s, k, 64);
    float inv = 1.0f / s;
    row[lane]        = v0 * inv;
    row[lane + 64]   = v1 * inv;
    row[lane + 128]  = v2 * inv;
    if (lane < 16) row[lane + 192] = v3 * inv;
}

// ---------------- K4t: t-apply (writes outT) ----------------
// grid (96, 96, 2) = (w, h, n); thread = c
__global__ __launch_bounds__(256) void k_at(
    const float* __restrict__ att, const float* __restrict__ vT, float* __restrict__ outT)
{
    const int w = blockIdx.x, h = blockIdx.y, n = blockIdx.z;
    const int tid = threadIdx.x;
    __shared__ float A[16][16];
    {
        int t = tid >> 4, s = tid & 15;
        A[t][s] = att[((size_t)(n * Tt + t) * HW + h * Ww + w) * Ssz + s];
    }
    __syncthreads();
    const int c = tid;
    float acc[16];
#pragma unroll
    for (int t = 0; t < 16; ++t) acc[t] = 0.f;
    for (int s = 0; s < 16; ++s) {
        float vv = vT[((size_t)(n * Tt + s) * HW + h * Ww + w) * 256 + c];
#pragma unroll
        for (int t = 0; t < 16; ++t) acc[t] += A[t][s] * vv;
    }
#pragma unroll
    for (int t = 0; t < 16; ++t)
        outT[((size_t)(n * Tt + t) * HW + h * Ww + w) * 256 + c] = acc[t];
}

// ---------------- K4h: h-apply (accumulates into outT) ----------------
// grid (96, 16, 8): w=bx, t=by, n=bz>>2, cq=bz&3 (64-channel quarter)
__global__ __launch_bounds__(256) void k_ah(
    const float* __restrict__ att, const float* __restrict__ vT, float* __restrict__ outT)
{
    const int w = blockIdx.x, t = blockIdx.y;
    const int n = blockIdx.z >> 2, cq = blockIdx.z & 3;
    const int tid = threadIdx.x, tx = tid & 15, ty = tid >> 4;
    extern __shared__ float sm[];
    float* V = sm;            // [96][64]
    float* A = sm + 96 * 64;  // [96][97]
#pragma unroll
    for (int it = 0; it < 6; ++it) {
        int j = (tid >> 4) + 16 * it;
        int c4 = (tid & 15) * 4;
        float4 vv = *(const float4*)(vT + ((size_t)(n * Tt + t) * HW + j * Ww + w) * 256 + cq * 64 + c4);
        *(float4*)(V + j * 64 + c4) = vv;
    }
    for (int idx = tid; idx < 96 * 96; idx += 256) {
        int hh = idx / 96, j = idx - hh * 96;
        A[hh * 97 + j] = att[((size_t)(n * Tt + t) * HW + hh * Ww + w) * Ssz + 16 + j];
    }
    __syncthreads();
    float acc[6][4];
#pragma unroll
    for (int i = 0; i < 6; ++i)
#pragma unroll
        for (int j = 0; j < 4; ++j) acc[i][j] = 0.f;
    for (int j = 0; j < 96; ++j) {
        float vf[4], af[6];
#pragma unroll
        for (int i = 0; i < 4; ++i) vf[i] = V[j * 64 + tx + 16 * i];
#pragma unroll
        for (int ih = 0; ih < 6; ++ih) af[ih] = A[(ty + 16 * ih) * 97 + j];
#pragma unroll
        for (int ih = 0; ih < 6; ++ih)
#pragma unroll
            for (int i = 0; i < 4; ++i) acc[ih][i] += af[ih] * vf[i];
    }
#pragma unroll
    for (int ih = 0; ih < 6; ++ih)
#pragma unroll
        for (int i = 0; i < 4; ++i) {
            int h = ty + 16 * ih, c = cq * 64 + tx + 16 * i;
            size_t o = ((size_t)(n * Tt + t) * HW + h * Ww + w) * 256 + c;
            outT[o] += acc[ih][i];
        }
}

// ---------------- K4w: w-apply (accumulates into outT) ----------------
// grid (96, 16, 8): h=bx, t=by, n=bz>>2, cq=bz&3
__global__ __launch_bounds__(256) void k_aw(
    const float* __restrict__ att, const float* __restrict__ vT, float* __restrict__ outT)
{
    const int h = blockIdx.x, t = blockIdx.y;
    const int n = blockIdx.z >> 2, cq = blockIdx.z & 3;
    const int tid = threadIdx.x, tx = tid & 15, ty = tid >> 4;
    extern __shared__ float sm[];
    float* V = sm;            // [96][64]
    float* A = sm + 96 * 64;  // [96][97]
#pragma unroll
    for (int it = 0; it < 6; ++it) {
        int j = (tid >> 4) + 16 * it;
        int c4 = (tid & 15) * 4;
        float4 vv = *(const float4*)(vT + ((size_t)(n * Tt + t) * HW + h * Ww + j) * 256 + cq * 64 + c4);
        *(float4*)(V + j * 64 + c4) = vv;
    }
    for (int idx = tid; idx < 96 * 96; idx += 256) {
        int ww = idx / 96, j = idx - ww * 96;
        A[ww * 97 + j] = att[((size_t)(n * Tt + t) * HW + h * Ww + ww) * Ssz + 112 + j];
    }
    __syncthreads();
    float acc[6][4];
#pragma unroll
    for (int i = 0; i < 6; ++i)
#pragma unroll
        for (int j = 0; j < 4; ++j) acc[i][j] = 0.f;
    for (int j = 0; j < 96; ++j) {
        float vf[4], af[6];
#pragma unroll
        for (int i = 0; i < 4; ++i) vf[i] = V[j * 64 + tx + 16 * i];
#pragma unroll
        for (int iw = 0; iw < 6; ++iw) af[iw] = A[(ty + 16 * iw) * 97 + j];
#pragma unroll
        for (int iw = 0; iw < 6; ++iw)
#pragma unroll
            for (int i = 0; i < 4; ++i) acc[iw][i] += af[iw] * vf[i];
    }
#pragma unroll
    for (int iw = 0; iw < 6; ++iw)
#pragma unroll
        for (int i = 0; i < 4; ++i) {
            int w = ty + 16 * iw, c = cq * 64 + tx + 16 * i;
            size_t o = ((size_t)(n * Tt + t) * HW + h * Ww + w) * 256 + c;
            outT[o] += acc[iw][i];
        }
}

// ---------------- K5: transpose + gamma ----------------
// grid (96, 16, 4): h=bx, t=by, n=bz>>1, ch=bz&1 (128-channel half)
__global__ __launch_bounds__(256) void k_out(
    const float* __restrict__ outT, const float* __restrict__ gamma, float* __restrict__ out)
{
    const int h = blockIdx.x, t = blockIdx.y;
    const int n = blockIdx.z >> 1, ch = blockIdx.z & 1;
    const int tid = threadIdx.x;
    extern __shared__ float sm[];   // tile [96][129]
    const float g = gamma[0];
#pragma unroll
    for (int it = 0; it < 12; ++it) {
        int w = (tid >> 5) + 8 * it;
        int c4 = (tid & 31) * 4;
        float4 vv = *(const float4*)(outT + ((size_t)(n * Tt + t) * HW + h * Ww + w) * 256 + ch * 128 + c4);
        sm[w * 129 + c4 + 0] = vv.x; sm[w * 129 + c4 + 1] = vv.y;
        sm[w * 129 + c4 + 2] = vv.z; sm[w * 129 + c4 + 3] = vv.w;
    }
    __syncthreads();
    for (int idx = tid; idx < 128 * 96; idx += 256) {
        int cl = idx / 96, w = idx - cl * 96;
        int c = ch * 128 + cl;
        out[(((size_t)n * Cc + c) * Tt + t) * HW + h * Ww + w] = g * sm[w * 129 + cl];
    }
}

extern "C" void kernel_launch(void* const* d_in, const int* in_sizes, int n_in,
                              void* d_out, int out_size, void* d_ws, size_t ws_size,
                              hipStream_t stream)
{
    const float* x     = (const float*)d_in[0];
    const float* Wq    = (const float*)d_in[1];
    const float* bq    = (const float*)d_in[2];
    const float* Wk    = (const float*)d_in[3];
    const float* bk    = (const float*)d_in[4];
    const float* Wv    = (const float*)d_in[5];
    const float* bv    = (const float*)d_in[6];
    const float* gamma = (const float*)d_in[7];
    float* out = (float*)d_out;

    float* wsf  = (float*)d_ws;
    float* qT   = wsf + QT_OFF;
    float* kT   = wsf + KT_OFF;
    float* vT   = wsf + VT_OFF;
    float* att  = wsf + ATT_OFF;
    float* outT = wsf + OUTT_OFF;

    dim3 blk(256);

    k_qkv<<<dim3(1152, 3, 2), blk, (32 * 128 + 128 * 33) * 4, stream>>>(
        x, Wq, bq, Wk, bk, Wv, bv, qT, kT, vT);

    k_et<<<dim3(96, 96, 2), blk, 2 * 16 * 65 * 4, stream>>>(qT, kT, att);
    k_eh<<<dim3(96, 16, 2), blk, 2 * 96 * 65 * 4, stream>>>(qT, kT, att);
    k_ew<<<dim3(96, 16, 2), blk, 2 * 96 * 65 * 4, stream>>>(qT, kT, att);

    k_softmax<<<dim3(73728), blk, 0, stream>>>(att);

    k_at<<<dim3(96, 96, 2), blk, 0, stream>>>(att, vT, outT);
    k_ah<<<dim3(96, 16, 8), blk, (96 * 64 + 96 * 97) * 4, stream>>>(att, vT, outT);
    k_aw<<<dim3(96, 16, 8), blk, (96 * 64 + 96 * 97) * 4, stream>>>(att, vT, outT);

    k_out<<<dim3(96, 16, 4), blk, 96 * 129 * 4, stream>>>(outT, gamma, out);
}

// Round 3
// 1726.135 us; speedup vs baseline: 1.4124x; 1.4124x over previous
//
#include <hip/hip_runtime.h>
#include <math.h>

// CrissCrossAttention3D  N=2 C=256 Ci=64 T=16 H=96 W=96 — bf16 MFMA round (fix: k_energy staging mod-768)
// qkv bf16 [n][p][384] (q 0-63 | k 64-127 | v 128-383), p = t*9216 + h*96 + w
// att fp32 [n][p][208]; attT/attH/attW bf16 axis-tiled; outT fp32 [n][p][256]
// ws layout (bytes):
//   QKV  [0            , 226,492,416)
//   ATTT [226,492,416  , 235,929,600)
//   ATTH [235,929,600  , 292,552,704)
//   ATTW [292,552,704  , 349,175,808)
//   ATT  [349,175,808  , 594,542,592)   fp32 energies (dead after softmax)
//   OUTT [349,175,808  , 651,165,696)   overlays ATT after softmax
//   WB   [651,165,696  , 651,362,304)   packed bf16 weights
//   BC   [651,362,304  , 651,363,840)   combined fp32 bias

namespace {
constexpr int Cc = 256, Tt = 16, Hh = 96, Ww = 96;
constexpr int HW = Hh * Ww;        // 9216
constexpr int THW = Tt * HW;       // 147456
constexpr int Ssz = 208;
constexpr float FNEG = -1.0e30f;

constexpr size_t QKV_B  = 0;
constexpr size_t ATTT_B = 226492416;
constexpr size_t ATTH_B = 235929600;
constexpr size_t ATTW_B = 292552704;
constexpr size_t ATT_B  = 349175808;
constexpr size_t OUTT_B = 349175808;
constexpr size_t WB_B   = 651165696;
constexpr size_t BC_B   = 651362304;
} // namespace

typedef __attribute__((ext_vector_type(8))) short short8;
typedef __attribute__((ext_vector_type(4))) float f32x4;

__device__ __forceinline__ unsigned f2bf(float f) {
    union { float f; unsigned u; } v; v.f = f;
    unsigned r = v.u + 0x7FFF + ((v.u >> 16) & 1);   // RN-even
    return r >> 16;
}
__device__ __forceinline__ float bf2f(unsigned short h) {
    union { unsigned u; float f; } v; v.u = ((unsigned)h) << 16;
    return v.f;
}

// ---------------- K0: pack W (fp32 -> bf16 [384][256]) + combined bias ----------------
__global__ __launch_bounds__(64) void k_pack(
    const float* __restrict__ Wq, const float* __restrict__ bq,
    const float* __restrict__ Wk, const float* __restrict__ bk,
    const float* __restrict__ Wv, const float* __restrict__ bv,
    unsigned short* __restrict__ Wb, float* __restrict__ bc)
{
    const int m = blockIdx.x, lane = threadIdx.x;
    const float* src; const float* bsrc; int r;
    if (m < 64)       { src = Wq; bsrc = bq; r = m; }
    else if (m < 128) { src = Wk; bsrc = bk; r = m - 64; }
    else              { src = Wv; bsrc = bv; r = m - 128; }
    float4 v = *(const float4*)(src + (size_t)r * 256 + lane * 4);
    unsigned short* dst = Wb + (size_t)m * 256 + lane * 4;
    dst[0] = (unsigned short)f2bf(v.x); dst[1] = (unsigned short)f2bf(v.y);
    dst[2] = (unsigned short)f2bf(v.z); dst[3] = (unsigned short)f2bf(v.w);
    if (lane == 0) bc[m] = bsrc[r];
}

// ---------------- K1: fused QKV projection, bf16 MFMA ----------------
// grid (1152, 2) block 512 (8 waves, 2x4).  BM=128 p, BN=384 m, BK=32.
__global__ __launch_bounds__(512) void k_gemm(
    const float* __restrict__ x, const unsigned short* __restrict__ Wb,
    const float* __restrict__ bc, unsigned short* __restrict__ qkv)
{
    const int pt = blockIdx.x, n = blockIdx.y;
    const int tid = threadIdx.x;
    const int wv = tid >> 6, lane = tid & 63;
    const int wr = wv >> 2, wc = wv & 3;
    const int lrow = lane & 15, lkg = lane >> 4;
    const int p0 = pt * 128;

    __shared__ float Xs[32][132];
    __shared__ unsigned short Ws[384 * 40];

    f32x4 acc[4][6];
#pragma unroll
    for (int mi = 0; mi < 4; ++mi)
#pragma unroll
        for (int ni = 0; ni < 6; ++ni) { f32x4 z = {0.f,0.f,0.f,0.f}; acc[mi][ni] = z; }

    for (int c0 = 0; c0 < 256; c0 += 32) {
#pragma unroll
        for (int it = 0; it < 2; ++it) {
            int CI = it * 512 + tid;            // 0..1023
            int c = CI >> 5, p4 = CI & 31;
            float4 xv = *(const float4*)(x + ((size_t)n * 256 + c0 + c) * THW + p0 + p4 * 4);
            *(float4*)(&Xs[c][p4 * 4]) = xv;
        }
#pragma unroll
        for (int it = 0; it < 3; ++it) {
            int CI = it * 512 + tid;            // 0..1535
            int r = CI >> 2, ck = CI & 3;
            uint4 wv4 = *(const uint4*)(Wb + (size_t)r * 256 + c0 + ck * 8);
            *(uint4*)(&Ws[r * 40 + ck * 8]) = wv4;
        }
        __syncthreads();

        short8 af[4];
#pragma unroll
        for (int mi = 0; mi < 4; ++mi) {
            int p = wr * 64 + mi * 16 + lrow;
            union { unsigned u[4]; short8 s; } pk;
#pragma unroll
            for (int jj = 0; jj < 4; ++jj) {
                float lo = Xs[lkg * 8 + jj * 2 + 0][p];
                float hi = Xs[lkg * 8 + jj * 2 + 1][p];
                pk.u[jj] = (f2bf(hi) << 16) | f2bf(lo);
            }
            af[mi] = pk.s;
        }
#pragma unroll
        for (int ni = 0; ni < 6; ++ni) {
            int m = wc * 96 + ni * 16 + lrow;
            short8 bfg = *(const short8*)(&Ws[m * 40 + lkg * 8]);
#pragma unroll
            for (int mi = 0; mi < 4; ++mi)
                acc[mi][ni] = __builtin_amdgcn_mfma_f32_16x16x32_bf16(af[mi], bfg, acc[mi][ni], 0, 0, 0);
        }
        __syncthreads();
    }

#pragma unroll
    for (int mi = 0; mi < 4; ++mi)
#pragma unroll
        for (int ni = 0; ni < 6; ++ni) {
            int m = wc * 96 + ni * 16 + lrow;
            float bias = bc[m];
#pragma unroll
            for (int q = 0; q < 4; ++q) {
                int p = p0 + wr * 64 + mi * 16 + lkg * 4 + q;
                qkv[((size_t)n * THW + p) * 384 + m] = (unsigned short)f2bf(acc[mi][ni][q] + bias);
            }
        }
}

// ---------------- K2t: e_t (VALU, small) ----------------
// grid (96, 96, 2) = (w, h, n)
__global__ __launch_bounds__(256) void k_et(
    const unsigned short* __restrict__ qkv, float* __restrict__ att)
{
    const int w = blockIdx.x, h = blockIdx.y, n = blockIdx.z;
    const int tid = threadIdx.x;
    __shared__ float QK[16][132];   // cols 0..63 q, 64..127 k
    {
        int t = tid >> 4, c8 = tid & 15;
        uint4 v = *(const uint4*)(qkv + ((size_t)n * THW + t * 9216 + h * 96 + w) * 384 + c8 * 8);
        const unsigned short* u = (const unsigned short*)&v;
#pragma unroll
        for (int j = 0; j < 8; ++j) QK[t][c8 * 8 + j] = bf2f(u[j]);
    }
    __syncthreads();
    const int t = tid >> 4, s = tid & 15;
    float acc = 0.f;
#pragma unroll 8
    for (int c = 0; c < 64; ++c) acc += QK[t][c] * QK[s][64 + c];
    att[((size_t)n * THW + t * 9216 + h * 96 + w) * 208 + s] = acc;
}

// ---------------- K2hw: e_h / e_w via MFMA ----------------
// axis 0 (H): grid (96=w, 16=t, 2=n), rows=h, step_p=96, att col0=16
// axis 1 (W): grid (96=h, 16=t, 2=n), rows=w, step_p=1,  att col0=112
__global__ __launch_bounds__(256) void k_energy(
    const unsigned short* __restrict__ qkv, float* __restrict__ att, int axis)
{
    const int bx = blockIdx.x, t = blockIdx.y, n = blockIdx.z;
    const int base_p = t * 9216 + (axis == 0 ? bx : bx * 96);
    const int step_p = (axis == 0 ? 96 : 1);
    const int col0   = (axis == 0 ? 16 : 112);
    const int tid = threadIdx.x, wv = tid >> 6, lane = tid & 63;
    const int wr = wv >> 1, wc = wv & 1;
    const int lrow = lane & 15, lkg = lane >> 4;

    __shared__ unsigned short Qs[96 * 72];
    __shared__ unsigned short Ks[96 * 72];

    // stage 96 rows x (64 q + 64 k) bf16
#pragma unroll
    for (int it = 0; it < 6; ++it) {
        int CI = it * 256 + tid;            // 0..1535
        int half = CI >= 768;
        int ci = CI - half * 768;           // FIX: proper mod-768 (was CI & 767)
        int r = ci >> 3, ck = ci & 7;
        uint4 v = *(const uint4*)(qkv + ((size_t)n * THW + base_p + r * step_p) * 384 + half * 64 + ck * 8);
        *(uint4*)((half ? Ks : Qs) + r * 72 + ck * 8) = v;
    }
    __syncthreads();

    f32x4 acc[3][3];
#pragma unroll
    for (int mi = 0; mi < 3; ++mi)
#pragma unroll
        for (int ni = 0; ni < 3; ++ni) { f32x4 z = {0.f,0.f,0.f,0.f}; acc[mi][ni] = z; }

#pragma unroll
    for (int ks = 0; ks < 2; ++ks) {
        short8 af[3], bfg[3];
#pragma unroll
        for (int mi = 0; mi < 3; ++mi)
            af[mi] = *(const short8*)(Qs + (wr * 48 + mi * 16 + lrow) * 72 + ks * 32 + lkg * 8);
#pragma unroll
        for (int ni = 0; ni < 3; ++ni)
            bfg[ni] = *(const short8*)(Ks + (wc * 48 + ni * 16 + lrow) * 72 + ks * 32 + lkg * 8);
#pragma unroll
        for (int mi = 0; mi < 3; ++mi)
#pragma unroll
            for (int ni = 0; ni < 3; ++ni)
                acc[mi][ni] = __builtin_amdgcn_mfma_f32_16x16x32_bf16(af[mi], bfg[ni], acc[mi][ni], 0, 0, 0);
    }

#pragma unroll
    for (int mi = 0; mi < 3; ++mi)
#pragma unroll
        for (int ni = 0; ni < 3; ++ni)
#pragma unroll
            for (int q = 0; q < 4; ++q) {
                int rrow = wr * 48 + mi * 16 + lkg * 4 + q;
                int s = wc * 48 + ni * 16 + lrow;
                float val = (s == rrow) ? FNEG : acc[mi][ni][q];
                att[((size_t)n * THW + base_p + rrow * step_p) * 208 + col0 + s] = val;
            }
}

// ---------------- K3: softmax over 208 + scatter to bf16 axis tiles ----------------
__global__ __launch_bounds__(256) void k_softmax(
    const float* __restrict__ att, unsigned short* __restrict__ attT,
    unsigned short* __restrict__ attH, unsigned short* __restrict__ attW)
{
    const int pos = blockIdx.x * 4 + (threadIdx.x >> 6);
    const int lane = threadIdx.x & 63;
    const float* row = att + (size_t)pos * Ssz;
    float v0 = row[lane];
    float v1 = row[lane + 64];
    float v2 = row[lane + 128];
    float v3 = (lane < 16) ? row[lane + 192] : -INFINITY;
    float m = fmaxf(fmaxf(v0, v1), fmaxf(v2, v3));
#pragma unroll
    for (int k = 32; k >= 1; k >>= 1) m = fmaxf(m, __shfl_xor(m, k, 64));
    v0 = expf(v0 - m); v1 = expf(v1 - m); v2 = expf(v2 - m);
    v3 = (lane < 16) ? expf(v3 - m) : 0.f;
    float s = v0 + v1 + v2 + v3;
#pragma unroll
    for (int k = 32; k >= 1; k >>= 1) s += __shfl_xor(s, k, 64);
    float inv = 1.0f / s;
    v0 *= inv; v1 *= inv; v2 *= inv; v3 *= inv;

    int n = pos / THW; int rem = pos - n * THW;
    int t = rem / 9216; int hw = rem - t * 9216;
    int h = hw / 96; int w = hw - h * 96;

    size_t tBase = (((size_t)n * 96 + h) * 96 + w) * 256 + t * 16;
    size_t hBase = (((size_t)n * 16 + t) * 96 + w) * 9216 + h * 96;
    size_t wBase = (((size_t)n * 16 + t) * 96 + h) * 9216 + w * 96;

    {
        int sI = lane;          // 0..63 : t-seg(0..15) or h-seg(0..47)
        unsigned short b = (unsigned short)f2bf(v0);
        if (sI < 16) attT[tBase + sI] = b; else attH[hBase + (sI - 16)] = b;
    }
    {
        int sI = lane + 64;     // h-seg(48..95) or w-seg(0..15)
        unsigned short b = (unsigned short)f2bf(v1);
        if (sI < 112) attH[hBase + (sI - 16)] = b; else attW[wBase + (sI - 112)] = b;
    }
    {
        int sI = lane + 128;    // w-seg(16..79)
        unsigned short b = (unsigned short)f2bf(v2);
        attW[wBase + (sI - 112)] = b;
    }
    if (lane < 16) {
        int sI = lane + 192;    // w-seg(80..95)
        attW[wBase + (sI - 112)] = (unsigned short)f2bf(v3);
    }
}

// ---------------- K4t: t-apply (VALU), WRITES outT ----------------
// grid (96, 96, 2) = (w, h, n); thread = c
__global__ __launch_bounds__(256) void k_at(
    const unsigned short* __restrict__ attT, const unsigned short* __restrict__ qkv,
    float* __restrict__ outT)
{
    const int w = blockIdx.x, h = blockIdx.y, n = blockIdx.z;
    const int tid = threadIdx.x;
    __shared__ float A[16][17];
    if (tid < 32) {
        uint4 v = *(const uint4*)(attT + (((size_t)n * 96 + h) * 96 + w) * 256 + tid * 8);
        const unsigned short* u = (const unsigned short*)&v;
#pragma unroll
        for (int j = 0; j < 8; ++j) { int e = tid * 8 + j; A[e >> 4][e & 15] = bf2f(u[j]); }
    }
    __syncthreads();
    const int c = tid;
    float acc[16];
#pragma unroll
    for (int t = 0; t < 16; ++t) acc[t] = 0.f;
    for (int s = 0; s < 16; ++s) {
        float vv = bf2f(qkv[((size_t)n * THW + s * 9216 + h * 96 + w) * 384 + 128 + c]);
#pragma unroll
        for (int t = 0; t < 16; ++t) acc[t] += A[t][s] * vv;
    }
#pragma unroll
    for (int t = 0; t < 16; ++t)
        outT[((size_t)n * THW + t * 9216 + h * 96 + w) * 256 + c] = acc[t];
}

// ---------------- K4hw: h/w-apply via MFMA, RMW outT ----------------
// grid (96, 16, 4): bx, t, bz = n*2+ch (128-channel half)
// axis 0 (H): bx=w, rows=h, step=96; axis 1 (W): bx=h, rows=w, step=1
__global__ __launch_bounds__(256) void k_apply(
    const unsigned short* __restrict__ attX, const unsigned short* __restrict__ qkv,
    float* __restrict__ outT, int axis)
{
    const int bx = blockIdx.x, t = blockIdx.y;
    const int n = blockIdx.z >> 1, ch = blockIdx.z & 1;
    const int base_p = t * 9216 + (axis == 0 ? bx : bx * 96);
    const int step_p = (axis == 0 ? 96 : 1);
    const int tid = threadIdx.x, wv = tid >> 6, lane = tid & 63;
    const int wr = wv >> 1, wc = wv & 1;
    const int lrow = lane & 15, lkg = lane >> 4;

    extern __shared__ unsigned short sm_u16[];
    unsigned short* A  = sm_u16;             // [96][104]
    unsigned short* VT = sm_u16 + 96 * 104;  // [128][104]

    const size_t attbase = (((size_t)n * 16 + t) * 96 + bx) * 9216;

#pragma unroll
    for (int it = 0; it < 5; ++it) {
        int CI = it * 256 + tid;
        if (CI < 1152) {
            uint4 v = *(const uint4*)(attX + attbase + CI * 8);
            int r = CI / 12, cc = CI - r * 12;
            *(uint4*)(A + r * 104 + cc * 8) = v;
        }
    }
#pragma unroll
    for (int it = 0; it < 6; ++it) {
        int CI = it * 256 + tid;            // 0..1535
        int s = CI >> 4, c8 = CI & 15;
        uint4 v = *(const uint4*)(qkv + ((size_t)n * THW + base_p + s * step_p) * 384 + 128 + ch * 128 + c8 * 8);
        const unsigned short* u = (const unsigned short*)&v;
#pragma unroll
        for (int jo = 0; jo < 8; ++jo) {
            int j = (jo + c8) & 7;
            VT[(c8 * 8 + j) * 104 + s] = u[j];
        }
    }
    __syncthreads();

    f32x4 acc[3][4];
#pragma unroll
    for (int mi = 0; mi < 3; ++mi)
#pragma unroll
        for (int ni = 0; ni < 4; ++ni) { f32x4 z = {0.f,0.f,0.f,0.f}; acc[mi][ni] = z; }

#pragma unroll
    for (int ks = 0; ks < 3; ++ks) {
        short8 af[3];
#pragma unroll
        for (int mi = 0; mi < 3; ++mi)
            af[mi] = *(const short8*)(A + (wr * 48 + mi * 16 + lrow) * 104 + ks * 32 + lkg * 8);
#pragma unroll
        for (int ni = 0; ni < 4; ++ni) {
            short8 bfg = *(const short8*)(VT + (wc * 64 + ni * 16 + lrow) * 104 + ks * 32 + lkg * 8);
#pragma unroll
            for (int mi = 0; mi < 3; ++mi)
                acc[mi][ni] = __builtin_amdgcn_mfma_f32_16x16x32_bf16(af[mi], bfg, acc[mi][ni], 0, 0, 0);
        }
    }

#pragma unroll
    for (int mi = 0; mi < 3; ++mi)
#pragma unroll
        for (int ni = 0; ni < 4; ++ni)
#pragma unroll
            for (int q = 0; q < 4; ++q) {
                int rrow = wr * 48 + mi * 16 + lkg * 4 + q;
                int c = ch * 128 + wc * 64 + ni * 16 + lrow;
                size_t o = ((size_t)n * THW + base_p + rrow * step_p) * 256 + c;
                outT[o] += acc[mi][ni][q];
            }
}

// ---------------- K5: transpose + gamma ----------------
// grid (96, 16, 4): h=bx, t=by, n=bz>>1, ch=bz&1 (128-channel half)
__global__ __launch_bounds__(256) void k_out(
    const float* __restrict__ outT, const float* __restrict__ gamma, float* __restrict__ out)
{
    const int h = blockIdx.x, t = blockIdx.y;
    const int n = blockIdx.z >> 1, ch = blockIdx.z & 1;
    const int tid = threadIdx.x;
    extern __shared__ float smf[];   // tile [96][129]
    const float g = gamma[0];
#pragma unroll
    for (int it = 0; it < 12; ++it) {
        int w = (tid >> 5) + 8 * it;
        int c4 = (tid & 31) * 4;
        float4 vv = *(const float4*)(outT + ((size_t)n * THW + t * 9216 + h * 96 + w) * 256 + ch * 128 + c4);
        smf[w * 129 + c4 + 0] = vv.x; smf[w * 129 + c4 + 1] = vv.y;
        smf[w * 129 + c4 + 2] = vv.z; smf[w * 129 + c4 + 3] = vv.w;
    }
    __syncthreads();
    for (int idx = tid; idx < 128 * 96; idx += 256) {
        int cl = idx / 96, w = idx - cl * 96;
        int c = ch * 128 + cl;
        out[(((size_t)n * Cc + c) * Tt + t) * HW + h * 96 + w] = g * smf[w * 129 + cl];
    }
}

extern "C" void kernel_launch(void* const* d_in, const int* in_sizes, int n_in,
                              void* d_out, int out_size, void* d_ws, size_t ws_size,
                              hipStream_t stream)
{
    const float* x     = (const float*)d_in[0];
    const float* Wq    = (const float*)d_in[1];
    const float* bq    = (const float*)d_in[2];
    const float* Wk    = (const float*)d_in[3];
    const float* bk    = (const float*)d_in[4];
    const float* Wv    = (const float*)d_in[5];
    const float* bv    = (const float*)d_in[6];
    const float* gamma = (const float*)d_in[7];
    float* out = (float*)d_out;

    char* ws = (char*)d_ws;
    unsigned short* qkv  = (unsigned short*)(ws + QKV_B);
    unsigned short* attT = (unsigned short*)(ws + ATTT_B);
    unsigned short* attH = (unsigned short*)(ws + ATTH_B);
    unsigned short* attW = (unsigned short*)(ws + ATTW_B);
    float*          att  = (float*)(ws + ATT_B);
    float*          outT = (float*)(ws + OUTT_B);
    unsigned short* Wb   = (unsigned short*)(ws + WB_B);
    float*          bc   = (float*)(ws + BC_B);

    k_pack<<<dim3(384), dim3(64), 0, stream>>>(Wq, bq, Wk, bk, Wv, bv, Wb, bc);

    k_gemm<<<dim3(1152, 2), dim3(512), 0, stream>>>(x, Wb, bc, qkv);

    k_et<<<dim3(96, 96, 2), dim3(256), 0, stream>>>(qkv, att);
    k_energy<<<dim3(96, 16, 2), dim3(256), 0, stream>>>(qkv, att, 0);
    k_energy<<<dim3(96, 16, 2), dim3(256), 0, stream>>>(qkv, att, 1);

    k_softmax<<<dim3(73728), dim3(256), 0, stream>>>(att, attT, attH, attW);

    k_at<<<dim3(96, 96, 2), dim3(256), 0, stream>>>(attT, qkv, outT);
    k_apply<<<dim3(96, 16, 4), dim3(256), (96 + 128) * 104 * 2, stream>>>(attH, qkv, outT, 0);
    k_apply<<<dim3(96, 16, 4), dim3(256), (96 + 128) * 104 * 2, stream>>>(attW, qkv, outT, 1);

    k_out<<<dim3(96, 16, 4), dim3(256), 96 * 129 * 4, stream>>>(outT, gamma, out);
}